// Round 7
// baseline (1083.639 us; speedup 1.0000x reference)
//
#include <hip/hip_runtime.h>
#include <hip/hip_bf16.h>

#define NC 80
#define NK 51
#define REG_MAX 16
#define MAX_DET 100
#define A_TOT 8400
#define BS 16

// out layout (float32): num[16] | boxes[16*100*4] | scores[16*100] | classes[16*100] | kpts[16*100*17*3]
#define OUT_NUM 0
#define OUT_BOX 16
#define OUT_SCORE (16 + 16*MAX_DET*4)
#define OUT_CLASS (OUT_SCORE + 16*MAX_DET)
#define OUT_KPT (OUT_CLASS + 16*MAX_DET)

static __device__ __forceinline__ unsigned long long mk_key(unsigned u, int a) {
    return ((unsigned long long)u << 32) | (unsigned)(0x7FFFFFFF - a);
}

// -------- Kernel 1 v7: PP=8 weight-broadcast tile, hand-pipelined features --------
// LDS balance (calibrated v1..v6): weight broadcasts cost 80oc x 8iter x 12cy
// = 7.7K LDS-cy/chunk/block regardless of split; VALU wall = 80*32*A/128 cy.
// VALU-bound requires PP >= 6 anchors/lane. Here: 8 waves x O=10 ocs, each
// lane 8 consecutive anchors (A=512/block). Per wave/iter: 10 broadcast
// ds_read_b128 (120cy) vs 320 FMA (640cy) -> CU LDS 960 < VALU 1280.
// v5/v6's killer (unprefetched feature loads) fixed by an EXPLICIT 2-bank
// register pipeline: fb[(c4+1)&1] loaded a full iteration (~1280cy) ahead.
// Weights double-buffered in LDS: global->reg at chunk top, ds_write +
// one barrier at chunk tail. Per-(oc,anchor) chain: bias then strictly
// ascending channel fmaf -> bit-identical to all prior rounds.
// L2 (C=512) split into 2 oc-halves (O=5) writing partial argmax to ws;
// topk merges (tie -> lower half = first-max).
template<int C, int A, int O>
static __device__ __forceinline__ void score_tile(
    const float* __restrict__ x, const float* __restrict__ w,
    const float* __restrict__ bias,
    int b, int a0, int oc_base,
    float* __restrict__ out_m, int* __restrict__ out_i,
    float* __restrict__ wsh, float* __restrict__ rm, int* __restrict__ ri)
{
    constexpr int NOC = 8 * O;       // ocs staged per block (80 or 40)
    constexpr int NCH = C / 32;
    constexpr int NF4 = NOC * 8;     // float4s per weight chunk

    int t = threadIdx.x;
    int lane = t & 63;
    int wv = t >> 6;
    int ocw = oc_base + wv * O;

    int aa = a0 + lane * 8;
    if (aa > A - 8) aa = A - 8;      // ragged tail: dup lanes, writes guarded
    const float* xb = x + (long)b * C * A + aa;

    float acc[O][8];
#pragma unroll
    for (int j = 0; j < O; ++j) {
        float bv = bias[ocw + j];
#pragma unroll
        for (int q = 0; q < 8; ++q) acc[j][q] = bv;
    }

    bool st0 = (t < NF4), st1 = (t + 512 < NF4);
    int o0 = t >> 3, q0 = t & 7;
    int o1 = (t + 512) >> 3, q1 = (t + 512) & 7;

    // prologue: stage chunk 0 weights + first feature bank
    float4 s0, s1;
    if (st0) s0 = *(const float4*)(w + (long)(oc_base + o0) * C + q0 * 4);
    if (st1) s1 = *(const float4*)(w + (long)(oc_base + o1) * C + q1 * 4);

    float4 fb[2][8];                 // [bank][cc*2 + half]; constant-indexed
#pragma unroll
    for (int cc = 0; cc < 4; ++cc) {
        fb[0][cc * 2]     = *(const float4*)(xb + (long)cc * A);
        fb[0][cc * 2 + 1] = *(const float4*)(xb + (long)cc * A + 4);
    }
    const float* fnext = xb + 4 * (long)A;

    if (st0) *(float4*)&wsh[o0 * 36 + q0 * 4] = s0;
    if (st1) *(float4*)&wsh[o1 * 36 + q1 * 4] = s1;
    __syncthreads();

    for (int kc = 0; kc < NCH; ++kc) {
        int buf = kc & 1;
        if (kc + 1 < NCH) {          // issue next chunk's weight loads now
            const float* wn = w + (long)(kc + 1) * 32;
            if (st0) s0 = *(const float4*)(wn + (long)(oc_base + o0) * C + q0 * 4);
            if (st1) s1 = *(const float4*)(wn + (long)(oc_base + o1) * C + q1 * 4);
        }
        const float* wp = wsh + buf * (NOC * 36) + (wv * O) * 36;
#pragma unroll
        for (int c4 = 0; c4 < 8; ++c4) {
            // prefetch next 4 channels into the other bank (crosses chunks)
            if (c4 < 7 || kc + 1 < NCH) {
#pragma unroll
                for (int cc = 0; cc < 4; ++cc) {
                    fb[(c4 + 1) & 1][cc * 2]     = *(const float4*)(fnext + (long)cc * A);
                    fb[(c4 + 1) & 1][cc * 2 + 1] = *(const float4*)(fnext + (long)cc * A + 4);
                }
                fnext += 4 * (long)A;
            }
            constexpr int DUMMY = 0; (void)DUMMY;
            const int p = c4 & 1;
#pragma unroll
            for (int j = 0; j < O; ++j) {
                float4 w4 = *(const float4*)(wp + j * 36 + c4 * 4);  // uniform broadcast
                float wc[4] = { w4.x, w4.y, w4.z, w4.w };
#pragma unroll
                for (int cc = 0; cc < 4; ++cc) {
                    float4 fl = fb[p][cc * 2], fh = fb[p][cc * 2 + 1];
                    // ascending-channel chain per (oc, anchor) - bit-identical
                    acc[j][0] = fmaf(wc[cc], fl.x, acc[j][0]);
                    acc[j][1] = fmaf(wc[cc], fl.y, acc[j][1]);
                    acc[j][2] = fmaf(wc[cc], fl.z, acc[j][2]);
                    acc[j][3] = fmaf(wc[cc], fl.w, acc[j][3]);
                    acc[j][4] = fmaf(wc[cc], fh.x, acc[j][4]);
                    acc[j][5] = fmaf(wc[cc], fh.y, acc[j][5]);
                    acc[j][6] = fmaf(wc[cc], fh.z, acc[j][6]);
                    acc[j][7] = fmaf(wc[cc], fh.w, acc[j][7]);
                }
            }
        }
        if (kc + 1 < NCH) {          // write staged weights, one barrier/chunk
            float* wd = wsh + (buf ^ 1) * (NOC * 36);
            if (st0) *(float4*)&wd[o0 * 36 + q0 * 4] = s0;
            if (st1) *(float4*)&wd[o1 * 36 + q1 * 4] = s1;
            __syncthreads();
        }
    }

    // per-lane argmax over wave's O ocs (first-max: ascending j, strict >)
#pragma unroll
    for (int q = 0; q < 8; ++q) {
        float m = acc[0][q]; int mi = 0;
#pragma unroll
        for (int j = 1; j < O; ++j)
            if (acc[j][q] > m) { m = acc[j][q]; mi = j; }
        rm[wv * 512 + lane * 8 + q] = m;
        ri[wv * 512 + lane * 8 + q] = ocw + mi;
    }
    __syncthreads();

    // cross-wave reduce: ascending wv = ascending oc keeps first-max
    {
        float bm = rm[t]; int bi = ri[t];
#pragma unroll
        for (int v = 1; v < 8; ++v) {
            float om = rm[v * 512 + t];
            if (om > bm) { bm = om; bi = ri[v * 512 + t]; }
        }
        int ga = a0 + t;
        if (ga < A) {
            out_m[ga] = 1.0f / (1.0f + expf(-bm));
            out_i[ga] = bi;
        }
    }
}

__global__ __launch_bounds__(512, 2) void scores_fused(
    const float* __restrict__ x0, const float* __restrict__ x1, const float* __restrict__ x2,
    const float* __restrict__ w0, const float* __restrict__ w1, const float* __restrict__ w2,
    const float* __restrict__ bias0, const float* __restrict__ bias1, const float* __restrict__ bias2,
    float* __restrict__ max_s,       // [BS][A_TOT] (anchors <8000 only)
    int* __restrict__ cls_id,
    float* __restrict__ l2m,         // [2][BS][400] partial sigmoid-max
    int* __restrict__ l2i)           // [2][BS][400] partial argmax
{
    __shared__ float wsh[2 * 80 * 36];   // 23 KB double-buffered weights (padded rows)
    __shared__ float rm[8 * 512];        // 16 KB
    __shared__ int   ri[8 * 512];        // 16 KB

    int bid = blockIdx.x;
    if (bid < 64) {                  // L1: 16 b x 4 tiles of 512 (tile3 ragged)
        int b = bid >> 2, tile = bid & 3;
        score_tile<256, 1600, 10>(x1, w1, bias1, b, tile * 512, 0,
            max_s + (long)b * A_TOT + 6400, cls_id + (long)b * A_TOT + 6400, wsh, rm, ri);
    } else if (bid < 96) {           // L2: 16 b x 2 oc-halves (40 ocs each)
        int r = bid - 64;
        int b = r >> 1, h = r & 1;
        score_tile<512, 400, 5>(x2, w2, bias2, b, 0, h * 40,
            l2m + ((long)h * BS + b) * 400, l2i + ((long)h * BS + b) * 400, wsh, rm, ri);
    } else {                         // L0: 16 b x 13 tiles of 512 (tile12 ragged)
        int r = bid - 96;
        int b = r / 13, tile = r - b * 13;
        score_tile<128, 6400, 10>(x0, w0, bias0, b, tile * 512, 0,
            max_s + (long)b * A_TOT, cls_id + (long)b * A_TOT, wsh, rm, ri);
    }
}

// -------- Kernel 2: exact top-100 radix select (256 threads) + L2 merge --------
__global__ __launch_bounds__(256) void topk_kernel(
    float* __restrict__ max_s,       // [BS][A_TOT] (L2 region filled here)
    int* __restrict__ cls_id,
    const float* __restrict__ l2m, const int* __restrict__ l2i,
    float* __restrict__ out,
    int* __restrict__ top_idx)       // [BS][MAX_DET]
{
    int b = blockIdx.x;
    int t = threadIdx.x;
    int lane = t & 63;
    int wv = t >> 6;

    // merge L2 oc-halves into max_s/cls_id (tie -> half A = lower ocs = first-max)
    for (int a = t; a < 400; a += 256) {
        float sA = l2m[(0 * BS + b) * 400 + a];
        float sB = l2m[(1 * BS + b) * 400 + a];
        int   iA = l2i[(0 * BS + b) * 400 + a];
        int   iB = l2i[(1 * BS + b) * 400 + a];
        bool ta = (sA >= sB);
        max_s[(long)b * A_TOT + 8000 + a] = ta ? sA : sB;
        cls_id[(long)b * A_TOT + 8000 + a] = ta ? iA : iB;
    }
    __syncthreads();

    __shared__ unsigned hist[4 * 256];
    __shared__ int tieIdx[A_TOT];
    __shared__ unsigned long long highKeys[128];
    __shared__ unsigned long long finalKeys[128];
    __shared__ int wmin[4];
    __shared__ unsigned s_prefix;
    __shared__ int s_k, s_nHigh, s_nTie, s_cnt, s_bcast;

    uint4 uu[9];
#pragma unroll
    for (int i = 0; i < 9; ++i) {
        int idx = t + i * 256;
        if (i < 8 || t < 52)
            uu[i] = *(const uint4*)((const unsigned*)(max_s + (long)b * A_TOT) + idx * 4);
        else
            uu[i] = make_uint4(0u, 0u, 0u, 0u);
    }

    if (t == 0) { s_prefix = 0; s_k = MAX_DET; s_nHigh = 0; s_nTie = 0; s_cnt = 0; }

    for (int pass = 0; pass < 4; ++pass) {
#pragma unroll
        for (int j = 0; j < 4; ++j) hist[t + j * 256] = 0;
        __syncthreads();

        unsigned pre = s_prefix;
        int k = s_k;
        int shHi = 32 - 8 * pass;
        int shD = 24 - 8 * pass;
#pragma unroll
        for (int i = 0; i < 9; ++i) {
            if (i < 8 || t < 52) {
                unsigned e[4] = { uu[i].x, uu[i].y, uu[i].z, uu[i].w };
#pragma unroll
                for (int j = 0; j < 4; ++j) {
                    bool cand = (pass == 0) ? true : ((e[j] >> shHi) == pre);
                    if (cand)
                        atomicAdd(&hist[(wv << 8) + ((e[j] >> shD) & 0xFF)], 1u);
                }
            }
        }
        __syncthreads();

        if (wv == 0) {
            unsigned c0 = 0, c1 = 0, c2 = 0, c3 = 0;
#pragma unroll
            for (int w = 0; w < 4; ++w) {
                const unsigned* hp = &hist[(w << 8) + lane * 4];
                c0 += hp[0]; c1 += hp[1]; c2 += hp[2]; c3 += hp[3];
            }
            unsigned s3 = c3, s2 = c2 + s3, s1 = c1 + s2, s0 = c0 + s1;
            unsigned tsum = s0;
#pragma unroll
            for (int off = 1; off < 64; off <<= 1) {
                unsigned o = __shfl_down(tsum, off, 64);
                if (lane + off < 64) tsum += o;
            }
            unsigned excl = tsum - s0;
            unsigned S0 = excl + s0, S1 = excl + s1, S2 = excl + s2, S3 = excl + s3;
            int ld = -1;
            unsigned uk = (unsigned)k;
            if (S3 >= uk)      ld = lane * 4 + 3;
            else if (S2 >= uk) ld = lane * 4 + 2;
            else if (S1 >= uk) ld = lane * 4 + 1;
            else if (S0 >= uk) ld = lane * 4 + 0;
            int d = ld;
#pragma unroll
            for (int off = 32; off > 0; off >>= 1) d = max(d, __shfl_xor(d, off, 64));
            int dn = d + 1;
            unsigned mine = 0;
            if (dn < 256 && lane == (dn >> 2)) {
                int e = dn & 3;
                mine = (e == 0) ? S0 : (e == 1) ? S1 : (e == 2) ? S2 : S3;
            }
#pragma unroll
            for (int off = 32; off > 0; off >>= 1) mine += __shfl_xor(mine, off, 64);
            if (lane == 0) {
                s_k = k - (int)mine;
                s_prefix = (pre << 8) | (unsigned)d;
            }
        }
        __syncthreads();
    }

    unsigned cut = s_prefix;
    int r = s_k;

#pragma unroll
    for (int i = 0; i < 9; ++i) {
        if (i < 8 || t < 52) {
            unsigned e[4] = { uu[i].x, uu[i].y, uu[i].z, uu[i].w };
#pragma unroll
            for (int j = 0; j < 4; ++j) {
                int a = (t + i * 256) * 4 + j;
                if (e[j] > cut) {
                    int p = atomicAdd(&s_nHigh, 1);
                    highKeys[p] = mk_key(e[j], a);
                } else if (e[j] == cut) {
                    int p = atomicAdd(&s_nTie, 1);
                    tieIdx[p] = a;
                }
            }
        }
    }
    __syncthreads();
    int m = s_nHigh;
    int nt = s_nTie;

    if (t < 128) finalKeys[t] = 0ull;
    __syncthreads();
    if (t < m) finalKeys[t] = highKeys[t];

    if (nt == r) {
        if (t < nt) finalKeys[m + t] = mk_key(cut, tieIdx[t]);
        __syncthreads();
    } else {
        __syncthreads();
        for (int j = 0; j < r; ++j) {
            int mn = 0x7FFFFFFF;
            for (int p = t; p < nt; p += 256) mn = min(mn, tieIdx[p]);
            for (int off = 32; off > 0; off >>= 1) mn = min(mn, __shfl_down(mn, off, 64));
            if (lane == 0) wmin[wv] = mn;
            __syncthreads();
            if (t == 0) {
                int v = min(min(wmin[0], wmin[1]), min(wmin[2], wmin[3]));
                s_bcast = v;
                finalKeys[m + j] = mk_key(cut, v);
            }
            __syncthreads();
            int v = s_bcast;
            for (int p = t; p < nt; p += 256)
                if (tieIdx[p] == v) tieIdx[p] = 0x7FFFFFFF;
            __syncthreads();
        }
    }

    for (int ksz = 2; ksz <= 128; ksz <<= 1) {
        for (int j = ksz >> 1; j > 0; j >>= 1) {
            if (t < 128) {
                int ixj = t ^ j;
                if (ixj > t) {
                    bool desc = ((t & ksz) == 0);
                    unsigned long long x = finalKeys[t], y = finalKeys[ixj];
                    bool sw = desc ? (x < y) : (x > y);
                    if (sw) { finalKeys[t] = y; finalKeys[ixj] = x; }
                }
            }
            __syncthreads();
        }
    }

    if (t < MAX_DET) {
        unsigned long long kk = finalKeys[t];
        float sc = __uint_as_float((unsigned)(kk >> 32));
        int a = 0x7FFFFFFF - (int)(kk & 0xFFFFFFFFull);
        out[OUT_SCORE + b * MAX_DET + t] = sc;
        out[OUT_CLASS + b * MAX_DET + t] = (float)cls_id[b * A_TOT + a];
        top_idx[b * MAX_DET + t] = a;
        if (sc > 0.25f) atomicAdd(&s_cnt, 1);
    }
    __syncthreads();
    if (t == 0) out[OUT_NUM + b] = (float)s_cnt;
}

// -------- Kernel 3: decode box + kpts for selected anchors (float4 dot) --------
__global__ __launch_bounds__(128) void decode_kernel(
    const float* __restrict__ x0, const float* __restrict__ x1, const float* __restrict__ x2,
    const float* __restrict__ w2_0, const float* __restrict__ b2_0,
    const float* __restrict__ w2_1, const float* __restrict__ b2_1,
    const float* __restrict__ w2_2, const float* __restrict__ b2_2,
    const float* __restrict__ w4_0, const float* __restrict__ b4_0,
    const float* __restrict__ w4_1, const float* __restrict__ b4_1,
    const float* __restrict__ w4_2, const float* __restrict__ b4_2,
    const int* __restrict__ top_idx,
    float* __restrict__ out)
{
    int b = blockIdx.y;
    int k = blockIdx.x;
    int a = top_idx[b * MAX_DET + k];

    const float* x; const float* w2; const float* bb2; const float* w4; const float* bb4;
    int C, A, W, a_local; float stride;
    if (a < 6400)      { x = x0; C = 128; A = 6400; W = 80; stride = 8.0f;  a_local = a;        w2 = w2_0; bb2 = b2_0; w4 = w4_0; bb4 = b4_0; }
    else if (a < 8000) { x = x1; C = 256; A = 1600; W = 40; stride = 16.0f; a_local = a - 6400; w2 = w2_1; bb2 = b2_1; w4 = w4_1; bb4 = b4_1; }
    else               { x = x2; C = 512; A = 400;  W = 20; stride = 32.0f; a_local = a - 8000; w2 = w2_2; bb2 = b2_2; w4 = w4_2; bb4 = b4_2; }

    __shared__ float fs[512];
    __shared__ float logits[64];
    __shared__ float kraw[NK];
    __shared__ float dist[4];

    int t = threadIdx.x;
    for (int c = t; c < C; c += 128)
        fs[c] = x[((long)b * C + c) * A + a_local];
    __syncthreads();

    if (t < 64 + NK) {
        const float* wrow; float acc;
        if (t < 64) { wrow = w2 + t * C; acc = bb2[t]; }
        else        { wrow = w4 + (t - 64) * C; acc = bb4[t - 64]; }
        for (int c = 0; c < C; c += 4) {
            float4 wv4 = *(const float4*)(wrow + c);
            float4 fv4 = *(const float4*)(&fs[c]);
            acc = fmaf(wv4.x, fv4.x, acc);
            acc = fmaf(wv4.y, fv4.y, acc);
            acc = fmaf(wv4.z, fv4.z, acc);
            acc = fmaf(wv4.w, fv4.w, acc);
        }
        if (t < 64) logits[t] = acc;
        else        kraw[t - 64] = acc;
    }
    __syncthreads();

    if (t < 4) {
        float mx = logits[t * 16];
#pragma unroll
        for (int r = 1; r < 16; ++r) mx = fmaxf(mx, logits[t * 16 + r]);
        float se = 0.0f, sw = 0.0f;
#pragma unroll
        for (int r = 0; r < 16; ++r) {
            float e = expf(logits[t * 16 + r] - mx);
            se += e; sw += e * (float)r;
        }
        dist[t] = sw / se;
    }
    __syncthreads();

    float ax = (float)(a_local % W) + 0.5f;
    float ay = (float)(a_local / W) + 0.5f;

    if (t == 0) {
        float x1c = ax - dist[0], y1c = ay - dist[1];
        float x2c = ax + dist[2], y2c = ay + dist[3];
        float* ob = out + OUT_BOX + ((long)b * MAX_DET + k) * 4;
        ob[0] = (x1c + x2c) * 0.5f * stride;
        ob[1] = (y1c + y2c) * 0.5f * stride;
        ob[2] = (x2c - x1c) * stride;
        ob[3] = (y2c - y1c) * stride;
    }
    if (t < 17) {
        float vx = kraw[t * 3], vy = kraw[t * 3 + 1], vv = kraw[t * 3 + 2];
        float gx = ax - 0.5f, gy = ay - 0.5f;
        float* ok = out + OUT_KPT + (((long)b * MAX_DET + k) * 17 + t) * 3;
        ok[0] = (vx * 2.0f + gx) * stride;
        ok[1] = (vy * 2.0f + gy) * stride;
        ok[2] = 1.0f / (1.0f + expf(-vv));
    }
}

extern "C" void kernel_launch(void* const* d_in, const int* in_sizes, int n_in,
                              void* d_out, int out_size, void* d_ws, size_t ws_size,
                              hipStream_t stream) {
    const float* x0 = (const float*)d_in[0];
    const float* x1 = (const float*)d_in[1];
    const float* x2 = (const float*)d_in[2];
    const float* w2[3] = {(const float*)d_in[3], (const float*)d_in[5], (const float*)d_in[7]};
    const float* b2[3] = {(const float*)d_in[4], (const float*)d_in[6], (const float*)d_in[8]};
    const float* w3[3] = {(const float*)d_in[9], (const float*)d_in[11], (const float*)d_in[13]};
    const float* b3[3] = {(const float*)d_in[10], (const float*)d_in[12], (const float*)d_in[14]};
    const float* w4[3] = {(const float*)d_in[15], (const float*)d_in[17], (const float*)d_in[19]};
    const float* b4[3] = {(const float*)d_in[16], (const float*)d_in[18], (const float*)d_in[20]};

    float* out = (float*)d_out;

    float* ws_maxs = (float*)d_ws;                     // [16][8400]
    int*   ws_cls  = (int*)(ws_maxs + BS * A_TOT);     // [16][8400]
    int*   ws_top  = (int*)(ws_cls + BS * A_TOT);      // [16][100]
    float* ws_l2m  = (float*)(ws_top + BS * MAX_DET);  // [2][16][400]
    int*   ws_l2i  = (int*)(ws_l2m + 2 * BS * 400);    // [2][16][400]

    // 64 (L1) + 32 (L2 oc-halves) + 208 (L0) = 304 blocks of 512 threads
    scores_fused<<<dim3(304), 512, 0, stream>>>(
        x0, x1, x2, w3[0], w3[1], w3[2], b3[0], b3[1], b3[2],
        ws_maxs, ws_cls, ws_l2m, ws_l2i);
    topk_kernel<<<dim3(BS), 256, 0, stream>>>(ws_maxs, ws_cls, ws_l2m, ws_l2i, out, ws_top);
    decode_kernel<<<dim3(MAX_DET, BS), 128, 0, stream>>>(
        x0, x1, x2,
        w2[0], b2[0], w2[1], b2[1], w2[2], b2[2],
        w4[0], b4[0], w4[1], b4[1], w4[2], b4[2],
        ws_top, out);
}

// Round 8
// 1077.664 us; speedup vs baseline: 1.0055x; 1.0055x over previous
//
#include <hip/hip_runtime.h>
#include <hip/hip_bf16.h>

#define NC 80
#define NK 51
#define REG_MAX 16
#define MAX_DET 100
#define A_TOT 8400
#define BS 16

// out layout (float32): num[16] | boxes[16*100*4] | scores[16*100] | classes[16*100] | kpts[16*100*17*3]
#define OUT_NUM 0
#define OUT_BOX 16
#define OUT_SCORE (16 + 16*MAX_DET*4)
#define OUT_CLASS (OUT_SCORE + 16*MAX_DET)
#define OUT_KPT (OUT_CLASS + 16*MAX_DET)

static __device__ __forceinline__ unsigned long long mk_key(unsigned u, int a) {
    return ((unsigned long long)u << 32) | (unsigned)(0x7FFFFFFF - a);
}

// -------- Kernel 1 v8: v7 structure with the register budget FIXED --------
// v7 was correct (passed, absmax 0) but __launch_bounds__(512,2) capped
// VGPR at 128 while the kernel needs ~180 (acc 80 + fb 64 + staging) ->
// accumulator/feature-bank spill -> 2.5 GB scratch traffic/dispatch ->
// 885 us at VALUBusy 3.6%. Fix: (512,1) -> 2 waves/SIMD -> 256 VGPR cap,
// no spill, 1 block/CU. The structure was designed for exactly that
// occupancy: feature latency hidden by the explicit 2-bank prefetch
// (~1280 cy ahead), weight latency by LDS double-buffering. Steady-state
// model: per c4-iter/wave 10 broadcast ds_read_b128 (120 cy, CU duty
// 0.75) vs 320 FMA (640 cy) -> VALU-bound.
// Per-(oc,anchor) chain: bias then strictly ascending channel fmaf ->
// bit-identical to all prior rounds. L2 (C=512) split into 2 oc-halves
// (O=5) writing partial argmax to ws; topk merges (tie -> lower half).
template<int C, int A, int O>
static __device__ __forceinline__ void score_tile(
    const float* __restrict__ x, const float* __restrict__ w,
    const float* __restrict__ bias,
    int b, int a0, int oc_base,
    float* __restrict__ out_m, int* __restrict__ out_i,
    float* __restrict__ wsh, float* __restrict__ rm, int* __restrict__ ri)
{
    constexpr int NOC = 8 * O;       // ocs staged per block (80 or 40)
    constexpr int NCH = C / 32;
    constexpr int NF4 = NOC * 8;     // float4s per weight chunk

    int t = threadIdx.x;
    int lane = t & 63;
    int wv = t >> 6;
    int ocw = oc_base + wv * O;

    int aa = a0 + lane * 8;
    if (aa > A - 8) aa = A - 8;      // ragged tail: dup lanes, writes guarded
    const float* xb = x + (long)b * C * A + aa;

    float acc[O][8];
#pragma unroll
    for (int j = 0; j < O; ++j) {
        float bv = bias[ocw + j];
#pragma unroll
        for (int q = 0; q < 8; ++q) acc[j][q] = bv;
    }

    bool st0 = (t < NF4), st1 = (t + 512 < NF4);
    int o0 = t >> 3, q0 = t & 7;
    int o1 = (t + 512) >> 3, q1 = (t + 512) & 7;

    // prologue: stage chunk 0 weights + first feature bank
    float4 s0, s1;
    if (st0) s0 = *(const float4*)(w + (long)(oc_base + o0) * C + q0 * 4);
    if (st1) s1 = *(const float4*)(w + (long)(oc_base + o1) * C + q1 * 4);

    float4 fb[2][8];                 // [bank][cc*2 + half]; constant-indexed
#pragma unroll
    for (int cc = 0; cc < 4; ++cc) {
        fb[0][cc * 2]     = *(const float4*)(xb + (long)cc * A);
        fb[0][cc * 2 + 1] = *(const float4*)(xb + (long)cc * A + 4);
    }
    const float* fnext = xb + 4 * (long)A;

    if (st0) *(float4*)&wsh[o0 * 36 + q0 * 4] = s0;
    if (st1) *(float4*)&wsh[o1 * 36 + q1 * 4] = s1;
    __syncthreads();

    for (int kc = 0; kc < NCH; ++kc) {
        int buf = kc & 1;
        if (kc + 1 < NCH) {          // issue next chunk's weight loads now
            const float* wn = w + (long)(kc + 1) * 32;
            if (st0) s0 = *(const float4*)(wn + (long)(oc_base + o0) * C + q0 * 4);
            if (st1) s1 = *(const float4*)(wn + (long)(oc_base + o1) * C + q1 * 4);
        }
        const float* wp = wsh + buf * (NOC * 36) + (wv * O) * 36;
#pragma unroll
        for (int c4 = 0; c4 < 8; ++c4) {
            // prefetch next 4 channels into the other bank (crosses chunks)
            if (c4 < 7 || kc + 1 < NCH) {
#pragma unroll
                for (int cc = 0; cc < 4; ++cc) {
                    fb[(c4 + 1) & 1][cc * 2]     = *(const float4*)(fnext + (long)cc * A);
                    fb[(c4 + 1) & 1][cc * 2 + 1] = *(const float4*)(fnext + (long)cc * A + 4);
                }
                fnext += 4 * (long)A;
            }
            const int p = c4 & 1;
#pragma unroll
            for (int j = 0; j < O; ++j) {
                float4 w4 = *(const float4*)(wp + j * 36 + c4 * 4);  // uniform broadcast
                float wc[4] = { w4.x, w4.y, w4.z, w4.w };
#pragma unroll
                for (int cc = 0; cc < 4; ++cc) {
                    float4 fl = fb[p][cc * 2], fh = fb[p][cc * 2 + 1];
                    // ascending-channel chain per (oc, anchor) - bit-identical
                    acc[j][0] = fmaf(wc[cc], fl.x, acc[j][0]);
                    acc[j][1] = fmaf(wc[cc], fl.y, acc[j][1]);
                    acc[j][2] = fmaf(wc[cc], fl.z, acc[j][2]);
                    acc[j][3] = fmaf(wc[cc], fl.w, acc[j][3]);
                    acc[j][4] = fmaf(wc[cc], fh.x, acc[j][4]);
                    acc[j][5] = fmaf(wc[cc], fh.y, acc[j][5]);
                    acc[j][6] = fmaf(wc[cc], fh.z, acc[j][6]);
                    acc[j][7] = fmaf(wc[cc], fh.w, acc[j][7]);
                }
            }
        }
        if (kc + 1 < NCH) {          // write staged weights, one barrier/chunk
            float* wd = wsh + (buf ^ 1) * (NOC * 36);
            if (st0) *(float4*)&wd[o0 * 36 + q0 * 4] = s0;
            if (st1) *(float4*)&wd[o1 * 36 + q1 * 4] = s1;
            __syncthreads();
        }
    }

    // per-lane argmax over wave's O ocs (first-max: ascending j, strict >)
#pragma unroll
    for (int q = 0; q < 8; ++q) {
        float m = acc[0][q]; int mi = 0;
#pragma unroll
        for (int j = 1; j < O; ++j)
            if (acc[j][q] > m) { m = acc[j][q]; mi = j; }
        rm[wv * 512 + lane * 8 + q] = m;
        ri[wv * 512 + lane * 8 + q] = ocw + mi;
    }
    __syncthreads();

    // cross-wave reduce: ascending wv = ascending oc keeps first-max
    {
        float bm = rm[t]; int bi = ri[t];
#pragma unroll
        for (int v = 1; v < 8; ++v) {
            float om = rm[v * 512 + t];
            if (om > bm) { bm = om; bi = ri[v * 512 + t]; }
        }
        int ga = a0 + t;
        if (ga < A) {
            out_m[ga] = 1.0f / (1.0f + expf(-bm));
            out_i[ga] = bi;
        }
    }
}

__global__ __launch_bounds__(512, 1) void scores_fused(
    const float* __restrict__ x0, const float* __restrict__ x1, const float* __restrict__ x2,
    const float* __restrict__ w0, const float* __restrict__ w1, const float* __restrict__ w2,
    const float* __restrict__ bias0, const float* __restrict__ bias1, const float* __restrict__ bias2,
    float* __restrict__ max_s,       // [BS][A_TOT] (anchors <8000 only)
    int* __restrict__ cls_id,
    float* __restrict__ l2m,         // [2][BS][400] partial sigmoid-max
    int* __restrict__ l2i)           // [2][BS][400] partial argmax
{
    __shared__ float wsh[2 * 80 * 36];   // 23 KB double-buffered weights (padded rows)
    __shared__ float rm[8 * 512];        // 16 KB
    __shared__ int   ri[8 * 512];        // 16 KB

    int bid = blockIdx.x;
    if (bid < 64) {                  // L1: 16 b x 4 tiles of 512 (tile3 ragged)
        int b = bid >> 2, tile = bid & 3;
        score_tile<256, 1600, 10>(x1, w1, bias1, b, tile * 512, 0,
            max_s + (long)b * A_TOT + 6400, cls_id + (long)b * A_TOT + 6400, wsh, rm, ri);
    } else if (bid < 96) {           // L2: 16 b x 2 oc-halves (40 ocs each)
        int r = bid - 64;
        int b = r >> 1, h = r & 1;
        score_tile<512, 400, 5>(x2, w2, bias2, b, 0, h * 40,
            l2m + ((long)h * BS + b) * 400, l2i + ((long)h * BS + b) * 400, wsh, rm, ri);
    } else {                         // L0: 16 b x 13 tiles of 512 (tile12 ragged)
        int r = bid - 96;
        int b = r / 13, tile = r - b * 13;
        score_tile<128, 6400, 10>(x0, w0, bias0, b, tile * 512, 0,
            max_s + (long)b * A_TOT, cls_id + (long)b * A_TOT, wsh, rm, ri);
    }
}

// -------- Kernel 2: exact top-100 radix select (256 threads) + L2 merge --------
__global__ __launch_bounds__(256) void topk_kernel(
    float* __restrict__ max_s,       // [BS][A_TOT] (L2 region filled here)
    int* __restrict__ cls_id,
    const float* __restrict__ l2m, const int* __restrict__ l2i,
    float* __restrict__ out,
    int* __restrict__ top_idx)       // [BS][MAX_DET]
{
    int b = blockIdx.x;
    int t = threadIdx.x;
    int lane = t & 63;
    int wv = t >> 6;

    // merge L2 oc-halves into max_s/cls_id (tie -> half A = lower ocs = first-max)
    for (int a = t; a < 400; a += 256) {
        float sA = l2m[(0 * BS + b) * 400 + a];
        float sB = l2m[(1 * BS + b) * 400 + a];
        int   iA = l2i[(0 * BS + b) * 400 + a];
        int   iB = l2i[(1 * BS + b) * 400 + a];
        bool ta = (sA >= sB);
        max_s[(long)b * A_TOT + 8000 + a] = ta ? sA : sB;
        cls_id[(long)b * A_TOT + 8000 + a] = ta ? iA : iB;
    }
    __syncthreads();

    __shared__ unsigned hist[4 * 256];
    __shared__ int tieIdx[A_TOT];
    __shared__ unsigned long long highKeys[128];
    __shared__ unsigned long long finalKeys[128];
    __shared__ int wmin[4];
    __shared__ unsigned s_prefix;
    __shared__ int s_k, s_nHigh, s_nTie, s_cnt, s_bcast;

    uint4 uu[9];
#pragma unroll
    for (int i = 0; i < 9; ++i) {
        int idx = t + i * 256;
        if (i < 8 || t < 52)
            uu[i] = *(const uint4*)((const unsigned*)(max_s + (long)b * A_TOT) + idx * 4);
        else
            uu[i] = make_uint4(0u, 0u, 0u, 0u);
    }

    if (t == 0) { s_prefix = 0; s_k = MAX_DET; s_nHigh = 0; s_nTie = 0; s_cnt = 0; }

    for (int pass = 0; pass < 4; ++pass) {
#pragma unroll
        for (int j = 0; j < 4; ++j) hist[t + j * 256] = 0;
        __syncthreads();

        unsigned pre = s_prefix;
        int k = s_k;
        int shHi = 32 - 8 * pass;
        int shD = 24 - 8 * pass;
#pragma unroll
        for (int i = 0; i < 9; ++i) {
            if (i < 8 || t < 52) {
                unsigned e[4] = { uu[i].x, uu[i].y, uu[i].z, uu[i].w };
#pragma unroll
                for (int j = 0; j < 4; ++j) {
                    bool cand = (pass == 0) ? true : ((e[j] >> shHi) == pre);
                    if (cand)
                        atomicAdd(&hist[(wv << 8) + ((e[j] >> shD) & 0xFF)], 1u);
                }
            }
        }
        __syncthreads();

        if (wv == 0) {
            unsigned c0 = 0, c1 = 0, c2 = 0, c3 = 0;
#pragma unroll
            for (int w = 0; w < 4; ++w) {
                const unsigned* hp = &hist[(w << 8) + lane * 4];
                c0 += hp[0]; c1 += hp[1]; c2 += hp[2]; c3 += hp[3];
            }
            unsigned s3 = c3, s2 = c2 + s3, s1 = c1 + s2, s0 = c0 + s1;
            unsigned tsum = s0;
#pragma unroll
            for (int off = 1; off < 64; off <<= 1) {
                unsigned o = __shfl_down(tsum, off, 64);
                if (lane + off < 64) tsum += o;
            }
            unsigned excl = tsum - s0;
            unsigned S0 = excl + s0, S1 = excl + s1, S2 = excl + s2, S3 = excl + s3;
            int ld = -1;
            unsigned uk = (unsigned)k;
            if (S3 >= uk)      ld = lane * 4 + 3;
            else if (S2 >= uk) ld = lane * 4 + 2;
            else if (S1 >= uk) ld = lane * 4 + 1;
            else if (S0 >= uk) ld = lane * 4 + 0;
            int d = ld;
#pragma unroll
            for (int off = 32; off > 0; off >>= 1) d = max(d, __shfl_xor(d, off, 64));
            int dn = d + 1;
            unsigned mine = 0;
            if (dn < 256 && lane == (dn >> 2)) {
                int e = dn & 3;
                mine = (e == 0) ? S0 : (e == 1) ? S1 : (e == 2) ? S2 : S3;
            }
#pragma unroll
            for (int off = 32; off > 0; off >>= 1) mine += __shfl_xor(mine, off, 64);
            if (lane == 0) {
                s_k = k - (int)mine;
                s_prefix = (pre << 8) | (unsigned)d;
            }
        }
        __syncthreads();
    }

    unsigned cut = s_prefix;
    int r = s_k;

#pragma unroll
    for (int i = 0; i < 9; ++i) {
        if (i < 8 || t < 52) {
            unsigned e[4] = { uu[i].x, uu[i].y, uu[i].z, uu[i].w };
#pragma unroll
            for (int j = 0; j < 4; ++j) {
                int a = (t + i * 256) * 4 + j;
                if (e[j] > cut) {
                    int p = atomicAdd(&s_nHigh, 1);
                    highKeys[p] = mk_key(e[j], a);
                } else if (e[j] == cut) {
                    int p = atomicAdd(&s_nTie, 1);
                    tieIdx[p] = a;
                }
            }
        }
    }
    __syncthreads();
    int m = s_nHigh;
    int nt = s_nTie;

    if (t < 128) finalKeys[t] = 0ull;
    __syncthreads();
    if (t < m) finalKeys[t] = highKeys[t];

    if (nt == r) {
        if (t < nt) finalKeys[m + t] = mk_key(cut, tieIdx[t]);
        __syncthreads();
    } else {
        __syncthreads();
        for (int j = 0; j < r; ++j) {
            int mn = 0x7FFFFFFF;
            for (int p = t; p < nt; p += 256) mn = min(mn, tieIdx[p]);
            for (int off = 32; off > 0; off >>= 1) mn = min(mn, __shfl_down(mn, off, 64));
            if (lane == 0) wmin[wv] = mn;
            __syncthreads();
            if (t == 0) {
                int v = min(min(wmin[0], wmin[1]), min(wmin[2], wmin[3]));
                s_bcast = v;
                finalKeys[m + j] = mk_key(cut, v);
            }
            __syncthreads();
            int v = s_bcast;
            for (int p = t; p < nt; p += 256)
                if (tieIdx[p] == v) tieIdx[p] = 0x7FFFFFFF;
            __syncthreads();
        }
    }

    for (int ksz = 2; ksz <= 128; ksz <<= 1) {
        for (int j = ksz >> 1; j > 0; j >>= 1) {
            if (t < 128) {
                int ixj = t ^ j;
                if (ixj > t) {
                    bool desc = ((t & ksz) == 0);
                    unsigned long long x = finalKeys[t], y = finalKeys[ixj];
                    bool sw = desc ? (x < y) : (x > y);
                    if (sw) { finalKeys[t] = y; finalKeys[ixj] = x; }
                }
            }
            __syncthreads();
        }
    }

    if (t < MAX_DET) {
        unsigned long long kk = finalKeys[t];
        float sc = __uint_as_float((unsigned)(kk >> 32));
        int a = 0x7FFFFFFF - (int)(kk & 0xFFFFFFFFull);
        out[OUT_SCORE + b * MAX_DET + t] = sc;
        out[OUT_CLASS + b * MAX_DET + t] = (float)cls_id[b * A_TOT + a];
        top_idx[b * MAX_DET + t] = a;
        if (sc > 0.25f) atomicAdd(&s_cnt, 1);
    }
    __syncthreads();
    if (t == 0) out[OUT_NUM + b] = (float)s_cnt;
}

// -------- Kernel 3: decode box + kpts for selected anchors (float4 dot) --------
__global__ __launch_bounds__(128) void decode_kernel(
    const float* __restrict__ x0, const float* __restrict__ x1, const float* __restrict__ x2,
    const float* __restrict__ w2_0, const float* __restrict__ b2_0,
    const float* __restrict__ w2_1, const float* __restrict__ b2_1,
    const float* __restrict__ w2_2, const float* __restrict__ b2_2,
    const float* __restrict__ w4_0, const float* __restrict__ b4_0,
    const float* __restrict__ w4_1, const float* __restrict__ b4_1,
    const float* __restrict__ w4_2, const float* __restrict__ b4_2,
    const int* __restrict__ top_idx,
    float* __restrict__ out)
{
    int b = blockIdx.y;
    int k = blockIdx.x;
    int a = top_idx[b * MAX_DET + k];

    const float* x; const float* w2; const float* bb2; const float* w4; const float* bb4;
    int C, A, W, a_local; float stride;
    if (a < 6400)      { x = x0; C = 128; A = 6400; W = 80; stride = 8.0f;  a_local = a;        w2 = w2_0; bb2 = b2_0; w4 = w4_0; bb4 = b4_0; }
    else if (a < 8000) { x = x1; C = 256; A = 1600; W = 40; stride = 16.0f; a_local = a - 6400; w2 = w2_1; bb2 = b2_1; w4 = w4_1; bb4 = b4_1; }
    else               { x = x2; C = 512; A = 400;  W = 20; stride = 32.0f; a_local = a - 8000; w2 = w2_2; bb2 = b2_2; w4 = w4_2; bb4 = b4_2; }

    __shared__ float fs[512];
    __shared__ float logits[64];
    __shared__ float kraw[NK];
    __shared__ float dist[4];

    int t = threadIdx.x;
    for (int c = t; c < C; c += 128)
        fs[c] = x[((long)b * C + c) * A + a_local];
    __syncthreads();

    if (t < 64 + NK) {
        const float* wrow; float acc;
        if (t < 64) { wrow = w2 + t * C; acc = bb2[t]; }
        else        { wrow = w4 + (t - 64) * C; acc = bb4[t - 64]; }
        for (int c = 0; c < C; c += 4) {
            float4 wv4 = *(const float4*)(wrow + c);
            float4 fv4 = *(const float4*)(&fs[c]);
            acc = fmaf(wv4.x, fv4.x, acc);
            acc = fmaf(wv4.y, fv4.y, acc);
            acc = fmaf(wv4.z, fv4.z, acc);
            acc = fmaf(wv4.w, fv4.w, acc);
        }
        if (t < 64) logits[t] = acc;
        else        kraw[t - 64] = acc;
    }
    __syncthreads();

    if (t < 4) {
        float mx = logits[t * 16];
#pragma unroll
        for (int r = 1; r < 16; ++r) mx = fmaxf(mx, logits[t * 16 + r]);
        float se = 0.0f, sw = 0.0f;
#pragma unroll
        for (int r = 0; r < 16; ++r) {
            float e = expf(logits[t * 16 + r] - mx);
            se += e; sw += e * (float)r;
        }
        dist[t] = sw / se;
    }
    __syncthreads();

    float ax = (float)(a_local % W) + 0.5f;
    float ay = (float)(a_local / W) + 0.5f;

    if (t == 0) {
        float x1c = ax - dist[0], y1c = ay - dist[1];
        float x2c = ax + dist[2], y2c = ay + dist[3];
        float* ob = out + OUT_BOX + ((long)b * MAX_DET + k) * 4;
        ob[0] = (x1c + x2c) * 0.5f * stride;
        ob[1] = (y1c + y2c) * 0.5f * stride;
        ob[2] = (x2c - x1c) * stride;
        ob[3] = (y2c - y1c) * stride;
    }
    if (t < 17) {
        float vx = kraw[t * 3], vy = kraw[t * 3 + 1], vv = kraw[t * 3 + 2];
        float gx = ax - 0.5f, gy = ay - 0.5f;
        float* ok = out + OUT_KPT + (((long)b * MAX_DET + k) * 17 + t) * 3;
        ok[0] = (vx * 2.0f + gx) * stride;
        ok[1] = (vy * 2.0f + gy) * stride;
        ok[2] = 1.0f / (1.0f + expf(-vv));
    }
}

extern "C" void kernel_launch(void* const* d_in, const int* in_sizes, int n_in,
                              void* d_out, int out_size, void* d_ws, size_t ws_size,
                              hipStream_t stream) {
    const float* x0 = (const float*)d_in[0];
    const float* x1 = (const float*)d_in[1];
    const float* x2 = (const float*)d_in[2];
    const float* w2[3] = {(const float*)d_in[3], (const float*)d_in[5], (const float*)d_in[7]};
    const float* b2[3] = {(const float*)d_in[4], (const float*)d_in[6], (const float*)d_in[8]};
    const float* w3[3] = {(const float*)d_in[9], (const float*)d_in[11], (const float*)d_in[13]};
    const float* b3[3] = {(const float*)d_in[10], (const float*)d_in[12], (const float*)d_in[14]};
    const float* w4[3] = {(const float*)d_in[15], (const float*)d_in[17], (const float*)d_in[19]};
    const float* b4[3] = {(const float*)d_in[16], (const float*)d_in[18], (const float*)d_in[20]};

    float* out = (float*)d_out;

    float* ws_maxs = (float*)d_ws;                     // [16][8400]
    int*   ws_cls  = (int*)(ws_maxs + BS * A_TOT);     // [16][8400]
    int*   ws_top  = (int*)(ws_cls + BS * A_TOT);      // [16][100]
    float* ws_l2m  = (float*)(ws_top + BS * MAX_DET);  // [2][16][400]
    int*   ws_l2i  = (int*)(ws_l2m + 2 * BS * 400);    // [2][16][400]

    // 64 (L1) + 32 (L2 oc-halves) + 208 (L0) = 304 blocks of 512 threads
    scores_fused<<<dim3(304), 512, 0, stream>>>(
        x0, x1, x2, w3[0], w3[1], w3[2], b3[0], b3[1], b3[2],
        ws_maxs, ws_cls, ws_l2m, ws_l2i);
    topk_kernel<<<dim3(BS), 256, 0, stream>>>(ws_maxs, ws_cls, ws_l2m, ws_l2i, out, ws_top);
    decode_kernel<<<dim3(MAX_DET, BS), 128, 0, stream>>>(
        x0, x1, x2,
        w2[0], b2[0], w2[1], b2[1], w2[2], b2[2],
        w4[0], b4[0], w4[1], b4[1], w4[2], b4[2],
        ws_top, out);
}